// Round 1
// baseline (5369.526 us; speedup 1.0000x reference)
//
#include <hip/hip_runtime.h>
#include <cstdint>

#define HW_ 160
#define NPIX (2*160*160)   // 51200 pixels (B*H*W)

// LDS xor-swizzle on dword index: row stride is 128 dwords, xor bits 2..4
// with (row>>2)&7 -> conflict-free aligned ds_read_b128 on both operands.
__device__ __forceinline__ int swz(int dw) {
  return dw ^ (((dw >> 9) & 7) << 2);
}

// C[m][n] = sum_k A[m][k] * W[n][k] (+ bias[n]), K = 128 fixed.
// BM = BN = 64, 256 threads, 4x4 register tile per thread.
template<int BM, int BN>
__global__ __launch_bounds__(256, 2)
void gemm128(const float* __restrict__ A, const float* __restrict__ W,
             const float* __restrict__ bias, float* __restrict__ C,
             int Ntotal) {
  __shared__ float As[BM * 128];
  __shared__ float Ws[BN * 128];
  const int t = threadIdx.x;
  const int row0 = blockIdx.x * BM;
  const int col0 = blockIdx.y * BN;

  // Tiles are fully contiguous in global memory (row length == K == 128).
  const float* Ag = A + (size_t)row0 * 128;
  const float* Wg = W + (size_t)col0 * 128;
#pragma unroll
  for (int i = 0; i < BM * 128 / 1024; ++i) {
    int flat = (t + i * 256) * 4;
    float4 v = *(const float4*)(Ag + flat);
    *(float4*)(As + swz(flat)) = v;
  }
#pragma unroll
  for (int i = 0; i < BN * 128 / 1024; ++i) {
    int flat = (t + i * 256) * 4;
    float4 v = *(const float4*)(Wg + flat);
    *(float4*)(Ws + swz(flat)) = v;
  }
  __syncthreads();

  const int tx = t & 15, ty = t >> 4;
  float acc[4][4] = {};
#pragma unroll
  for (int k = 0; k < 128; k += 4) {
    float4 a[4], w[4];
#pragma unroll
    for (int i = 0; i < 4; ++i) {
      int aa = (ty * 4 + i) * 128 + k;
      a[i] = *(const float4*)(As + swz(aa));
      int wa = (tx * 4 + i) * 128 + k;
      w[i] = *(const float4*)(Ws + swz(wa));
    }
#pragma unroll
    for (int i = 0; i < 4; ++i)
#pragma unroll
      for (int j = 0; j < 4; ++j) {
        acc[i][j] += a[i].x * w[j].x;
        acc[i][j] += a[i].y * w[j].y;
        acc[i][j] += a[i].z * w[j].z;
        acc[i][j] += a[i].w * w[j].w;
      }
  }

  float4 bv = make_float4(0.f, 0.f, 0.f, 0.f);
  if (bias) bv = *(const float4*)(bias + col0 + tx * 4);
#pragma unroll
  for (int i = 0; i < 4; ++i) {
    float4 o;
    o.x = acc[i][0] + bv.x;
    o.y = acc[i][1] + bv.y;
    o.z = acc[i][2] + bv.z;
    o.w = acc[i][3] + bv.w;
    *(float4*)(C + (size_t)(row0 + ty * 4 + i) * Ntotal + col0 + tx * 4) = o;
  }
}

// One wave per (pixel, dilation). lane = channel c in [0,64); head = c>>4.
// qkv layout: [pixel][384] with o = which*128 + dil*64 + c.
__global__ __launch_bounds__(256)
void attn_kernel(const float* __restrict__ qkv, float* __restrict__ yws) {
  const int t = threadIdx.x;
  const int lane = t & 63;
  const int wv = t >> 6;
  const int dil = blockIdx.y;
  const int r = (dil == 0) ? 1 : 2;
  const int p = blockIdx.x * 4 + wv;

  const int b = p / (HW_ * HW_);
  const int rem = p - b * HW_ * HW_;
  const int yy = rem / HW_;
  const int xx = rem - yy * HW_;

  const float scale = 0.25f;  // hd=16 -> 16^-0.5
  const int base = p * 384 + dil * 64 + lane;
  const float q = qkv[base];

  float lj[9], vj[9];
#pragma unroll
  for (int jy = 0; jy < 3; ++jy) {
#pragma unroll
    for (int jx = 0; jx < 3; ++jx) {
      const int j = jy * 3 + jx;
      const int ny = yy + (jy - 1) * r;
      const int nx = xx + (jx - 1) * r;
      const bool ib = (ny >= 0) && (ny < HW_) && (nx >= 0) && (nx < HW_);
      float kv = 0.f, vv = 0.f;
      if (ib) {
        const int nb = base + ((jy - 1) * r * HW_ + (jx - 1) * r) * 384;
        kv = qkv[nb + 128];
        vv = qkv[nb + 256];
      }
      // head-group (16 lanes) dot-product reduction
      float partial = q * kv;
      partial += __shfl_xor(partial, 1);
      partial += __shfl_xor(partial, 2);
      partial += __shfl_xor(partial, 4);
      partial += __shfl_xor(partial, 8);
      lj[j] = partial * scale;  // OOB neighbors: exactly 0, kept in softmax
      vj[j] = vv;
    }
  }

  float m = lj[0];
#pragma unroll
  for (int j = 1; j < 9; ++j) m = fmaxf(m, lj[j]);
  float s = 0.f, o = 0.f;
#pragma unroll
  for (int j = 0; j < 9; ++j) {
    const float e = __expf(lj[j] - m);
    s += e;
    o += e * vj[j];
  }
  yws[p * 128 + dil * 64 + lane] = o / s;
}

extern "C" void kernel_launch(void* const* d_in, const int* in_sizes, int n_in,
                              void* d_out, int out_size, void* d_ws, size_t ws_size,
                              hipStream_t stream) {
  const float* x      = (const float*)d_in[0];  // [2,160,160,128]
  const float* qkv_w  = (const float*)d_in[1];  // [384,128]
  const float* proj_w = (const float*)d_in[2];  // [128,128]
  const float* proj_b = (const float*)d_in[3];  // [128]
  float* out = (float*)d_out;                   // [2,160,160,128]

  float* qkv = (float*)d_ws;                       // NPIX*384 floats (~78.6 MB)
  float* yws = qkv + (size_t)NPIX * 384;           // NPIX*128 floats (~26.2 MB)

  // 1) QKV projection: [51200,128] x [384,128]^T -> [51200,384]
  gemm128<64, 64><<<dim3(NPIX / 64, 384 / 64), 256, 0, stream>>>(
      x, qkv_w, nullptr, qkv, 384);

  // 2) Dilated neighborhood attention -> yws [51200,128]
  attn_kernel<<<dim3(NPIX / 4, 2), 256, 0, stream>>>(qkv, yws);

  // 3) Output projection + bias: [51200,128] x [128,128]^T -> out
  gemm128<64, 64><<<dim3(NPIX / 64, 128 / 64), 256, 0, stream>>>(
      yws, proj_w, proj_b, out, 128);
}

// Round 2
// 169.358 us; speedup vs baseline: 31.7052x; 31.7052x over previous
//
#include <hip/hip_runtime.h>
#include <cstdint>

#define HW_ 160
#define NPIX (2*160*160)   // 51200 pixels (B*H*W)

typedef __attribute__((ext_vector_type(8))) short short8;
typedef __attribute__((ext_vector_type(4))) float f32x4;

// fp32 -> bf16 round-to-nearest-even
__device__ __forceinline__ unsigned short f2bf(float f) {
  union { float f; unsigned u; } v; v.f = f;
  unsigned r = v.u + 0x7fffu + ((v.u >> 16) & 1u);
  return (unsigned short)(r >> 16);
}

__device__ __forceinline__ short8 cvt8(const float4& x0, const float4& x1) {
  short8 h;
  h[0] = (short)f2bf(x0.x); h[1] = (short)f2bf(x0.y);
  h[2] = (short)f2bf(x0.z); h[3] = (short)f2bf(x0.w);
  h[4] = (short)f2bf(x1.x); h[5] = (short)f2bf(x1.y);
  h[6] = (short)f2bf(x1.z); h[7] = (short)f2bf(x1.w);
  return h;
}

// C[m][n] = sum_k A[m][k] * W[n][k] (+bias[n]); K=128 fixed, single LDS pass.
// Tile 128x64, 256 threads (4 waves, 2x2), mfma_f32_16x16x32_bf16.
// LDS xor-swizzle: byte ^= (row&7)<<4 on both write and read (G4 fix for D=128).
template<bool A_BF16>
__global__ __launch_bounds__(256, 3)
void gemm_mfma(const void* __restrict__ Av, const float* __restrict__ Wg,
               const float* __restrict__ bias, float* __restrict__ C, int N) {
  __shared__ short As[128 * 128];  // 32 KB
  __shared__ short Ws[64 * 128];   // 16 KB
  const int t = threadIdx.x;
  const int row0 = blockIdx.x * 128;
  const int col0 = blockIdx.y * 64;

  // ---- stage A tile (128 rows x 128 k) ----
  if constexpr (A_BF16) {
    const short* A = (const short*)Av + (size_t)row0 * 128;
#pragma unroll
    for (int it = 0; it < 8; ++it) {
      int f = t + it * 256;          // 16-byte chunk id (2048 total)
      int row = f >> 4;
      short8 v = *(const short8*)(A + f * 8);
      int dst = (row * 256 + (f & 15) * 16) ^ ((row & 7) << 4);
      *(short8*)((char*)As + dst) = v;
    }
  } else {
    const float* A = (const float*)Av + (size_t)row0 * 128;
#pragma unroll
    for (int it = 0; it < 8; ++it) {
      int f = t + it * 256;          // 32-byte fp32 chunk id
      int row = f >> 4;
      float4 x0 = *(const float4*)(A + f * 8);
      float4 x1 = *(const float4*)(A + f * 8 + 4);
      int dst = (row * 256 + (f & 15) * 16) ^ ((row & 7) << 4);
      *(short8*)((char*)As + dst) = cvt8(x0, x1);
    }
  }
  // ---- stage W tile (64 rows x 128 k), always fp32 ----
  {
    const float* W = Wg + (size_t)col0 * 128;
#pragma unroll
    for (int it = 0; it < 4; ++it) {
      int f = t + it * 256;
      int row = f >> 4;
      float4 x0 = *(const float4*)(W + f * 8);
      float4 x1 = *(const float4*)(W + f * 8 + 4);
      int dst = (row * 256 + (f & 15) * 16) ^ ((row & 7) << 4);
      *(short8*)((char*)Ws + dst) = cvt8(x0, x1);
    }
  }
  __syncthreads();

  const int lane = t & 63;
  const int w = t >> 6;
  const int wr = w & 1, wc = w >> 1;     // wave -> (row-half, col-half)
  const int lr = lane & 15, lk = lane >> 4;

  f32x4 acc[4][2];
#pragma unroll
  for (int m = 0; m < 4; ++m)
#pragma unroll
    for (int n = 0; n < 2; ++n) acc[m][n] = 0.f;

#pragma unroll
  for (int kk = 0; kk < 4; ++kk) {       // K = 4 x 32
    short8 a[4], b[2];
#pragma unroll
    for (int m = 0; m < 4; ++m) {
      int row = wr * 64 + m * 16 + lr;
      int off = (row * 256 + kk * 64 + lk * 16) ^ ((row & 7) << 4);
      a[m] = *(const short8*)((const char*)As + off);
    }
#pragma unroll
    for (int n = 0; n < 2; ++n) {
      int row = wc * 32 + n * 16 + lr;
      int off = (row * 256 + kk * 64 + lk * 16) ^ ((row & 7) << 4);
      b[n] = *(const short8*)((const char*)Ws + off);
    }
#pragma unroll
    for (int m = 0; m < 4; ++m)
#pragma unroll
      for (int n = 0; n < 2; ++n)
        acc[m][n] = __builtin_amdgcn_mfma_f32_16x16x32_bf16(a[m], b[n], acc[m][n], 0, 0, 0);
  }

  // ---- epilogue: C/D layout col = lane&15, row = (lane>>4)*4 + i ----
#pragma unroll
  for (int n = 0; n < 2; ++n) {
    int ccol = col0 + wc * 32 + n * 16 + lr;
    float bv = bias ? bias[ccol] : 0.f;
#pragma unroll
    for (int m = 0; m < 4; ++m) {
      int crow = row0 + wr * 64 + m * 16 + lk * 4;
#pragma unroll
      for (int i = 0; i < 4; ++i)
        C[(size_t)(crow + i) * N + ccol] = acc[m][n][i] + bv;
    }
  }
}

// One wave per (pixel, dilation). lane = channel c in [0,64); head = c>>4.
// qkv layout: [pixel][384], o = which*128 + dil*64 + c. Reads fp32, writes bf16.
__global__ __launch_bounds__(256)
void attn_kernel(const float* __restrict__ qkv, unsigned short* __restrict__ yws) {
  const int t = threadIdx.x;
  const int lane = t & 63;
  const int wv = t >> 6;
  const int dil = blockIdx.y;
  const int r = (dil == 0) ? 1 : 2;
  const int p = blockIdx.x * 4 + wv;

  const int rem = p % (HW_ * HW_);
  const int yy = rem / HW_;
  const int xx = rem - yy * HW_;

  const float scale = 0.25f;  // hd=16 -> 16^-0.5
  const int base = p * 384 + dil * 64 + lane;
  const float q = qkv[base];

  float lj[9], vj[9];
#pragma unroll
  for (int jy = 0; jy < 3; ++jy) {
#pragma unroll
    for (int jx = 0; jx < 3; ++jx) {
      const int j = jy * 3 + jx;
      const int ny = yy + (jy - 1) * r;
      const int nx = xx + (jx - 1) * r;
      const bool ib = (ny >= 0) && (ny < HW_) && (nx >= 0) && (nx < HW_);
      float kv = 0.f, vv = 0.f;
      if (ib) {
        const int nb = base + ((jy - 1) * r * HW_ + (jx - 1) * r) * 384;
        kv = qkv[nb + 128];
        vv = qkv[nb + 256];
      }
      float partial = q * kv;                 // 16-lane head reduction
      partial += __shfl_xor(partial, 1);
      partial += __shfl_xor(partial, 2);
      partial += __shfl_xor(partial, 4);
      partial += __shfl_xor(partial, 8);
      lj[j] = partial * scale;                // OOB: exactly 0, kept in softmax
      vj[j] = vv;
    }
  }

  float m = lj[0];
#pragma unroll
  for (int j = 1; j < 9; ++j) m = fmaxf(m, lj[j]);
  float s = 0.f, o = 0.f;
#pragma unroll
  for (int j = 0; j < 9; ++j) {
    const float e = __expf(lj[j] - m);
    s += e;
    o += e * vj[j];
  }
  yws[p * 128 + dil * 64 + lane] = f2bf(o / s);
}

extern "C" void kernel_launch(void* const* d_in, const int* in_sizes, int n_in,
                              void* d_out, int out_size, void* d_ws, size_t ws_size,
                              hipStream_t stream) {
  const float* x      = (const float*)d_in[0];  // [2,160,160,128]
  const float* qkv_w  = (const float*)d_in[1];  // [384,128]
  const float* proj_w = (const float*)d_in[2];  // [128,128]
  const float* proj_b = (const float*)d_in[3];  // [128]
  float* out = (float*)d_out;                   // [2,160,160,128] fp32

  float* qkv = (float*)d_ws;                                   // NPIX*384 fp32 (78.6 MB)
  unsigned short* yws = (unsigned short*)(qkv + (size_t)NPIX * 384);  // NPIX*128 bf16 (13.1 MB)

  // 1) QKV projection: [51200,128] x [384,128]^T -> [51200,384] fp32
  gemm_mfma<false><<<dim3(NPIX / 128, 384 / 64), 256, 0, stream>>>(
      x, qkv_w, nullptr, qkv, 384);

  // 2) Dilated neighborhood attention -> yws [51200,128] bf16
  attn_kernel<<<dim3(NPIX / 4, 2), 256, 0, stream>>>(qkv, yws);

  // 3) Output projection + bias: [51200,128] x [128,128]^T -> out fp32
  gemm_mfma<true><<<dim3(NPIX / 128, 128 / 64), 256, 0, stream>>>(
      yws, proj_w, proj_b, out, 128);
}

// Round 3
// 168.219 us; speedup vs baseline: 31.9199x; 1.0068x over previous
//
#include <hip/hip_runtime.h>
#include <cstdint>

#define HW_ 160
#define NPIX (2*160*160)   // 51200 pixels (B*H*W)

typedef __attribute__((ext_vector_type(8))) short short8;
typedef __attribute__((ext_vector_type(4))) float f32x4;

// fp32 -> bf16 round-to-nearest-even
__device__ __forceinline__ unsigned short f2bf(float f) {
  union { float f; unsigned u; } v; v.f = f;
  unsigned r = v.u + 0x7fffu + ((v.u >> 16) & 1u);
  return (unsigned short)(r >> 16);
}
__device__ __forceinline__ float bf2f(unsigned short u) {
  union { unsigned u; float f; } v; v.u = ((unsigned)u) << 16;
  return v.f;
}

__device__ __forceinline__ short8 cvt8(const float4& x0, const float4& x1) {
  short8 h;
  h[0] = (short)f2bf(x0.x); h[1] = (short)f2bf(x0.y);
  h[2] = (short)f2bf(x0.z); h[3] = (short)f2bf(x0.w);
  h[4] = (short)f2bf(x1.x); h[5] = (short)f2bf(x1.y);
  h[6] = (short)f2bf(x1.z); h[7] = (short)f2bf(x1.w);
  return h;
}

// ---------------------------------------------------------------------------
// GEMM1: qkv_t[o][p] = sum_k x[p][k] * qkv_w[o][k], output TRANSPOSED bf16.
// Block = 64 pixels; x staged once in LDS; loop over 6 o-tiles of 64.
// Operand-swapped MFMA: mfma(W_frag, X_frag) -> D row = o, col = pixel.
// ---------------------------------------------------------------------------
__global__ __launch_bounds__(256, 2)
void qkv_gemm(const float* __restrict__ x, const float* __restrict__ w,
              unsigned short* __restrict__ qt) {
  __shared__ short As[64 * 128];  // 16 KB, xor-swizzled
  const int t = threadIdx.x;
  const int p0 = blockIdx.x * 64;

  const float* A = x + (size_t)p0 * 128;
#pragma unroll
  for (int i = 0; i < 4; ++i) {
    int f = t + i * 256;           // 16B-chunk id (1024 total)
    int row = f >> 4;
    float4 x0 = *(const float4*)(A + f * 8);
    float4 x1 = *(const float4*)(A + f * 8 + 4);
    int dst = (row * 256 + (f & 15) * 16) ^ ((row & 7) << 4);
    *(short8*)((char*)As + dst) = cvt8(x0, x1);
  }
  __syncthreads();

  const int lane = t & 63, wv = t >> 6;
  const int wp = wv & 1, wc = wv >> 1;   // pixel-half / o-half
  const int lr = lane & 15, lk = lane >> 4;

  // hoist pixel-fragments (constant across o-loop)
  short8 af[2][4];
#pragma unroll
  for (int m = 0; m < 2; ++m)
#pragma unroll
    for (int kk = 0; kk < 4; ++kk) {
      int row = wp * 32 + m * 16 + lr;
      int off = (row * 256 + kk * 64 + lk * 16) ^ ((row & 7) << 4);
      af[m][kk] = *(const short8*)((const char*)As + off);
    }

#pragma unroll
  for (int it = 0; it < 6; ++it) {
    const int o0 = it * 64 + wc * 32;
    short8 bfr[2][4];
#pragma unroll
    for (int n = 0; n < 2; ++n) {
      const float* wr_ = w + (size_t)(o0 + n * 16 + lr) * 128;
#pragma unroll
      for (int kk = 0; kk < 4; ++kk) {
        float4 a0 = *(const float4*)(wr_ + kk * 32 + lk * 8);
        float4 a1 = *(const float4*)(wr_ + kk * 32 + lk * 8 + 4);
        bfr[n][kk] = cvt8(a0, a1);
      }
    }
    f32x4 acc[2][2];
#pragma unroll
    for (int n = 0; n < 2; ++n)
#pragma unroll
      for (int m = 0; m < 2; ++m) acc[n][m] = 0.f;
#pragma unroll
    for (int kk = 0; kk < 4; ++kk)
#pragma unroll
      for (int n = 0; n < 2; ++n)
#pragma unroll
        for (int m = 0; m < 2; ++m)
          acc[n][m] = __builtin_amdgcn_mfma_f32_16x16x32_bf16(
              bfr[n][kk], af[m][kk], acc[n][m], 0, 0, 0);
    // epilogue: D row = o (lk*4+i), col = pixel (lr). bf16 scatter; L2 merges.
#pragma unroll
    for (int n = 0; n < 2; ++n)
#pragma unroll
      for (int m = 0; m < 2; ++m) {
        int ob = o0 + n * 16 + lk * 4;
        int p = p0 + wp * 32 + m * 16 + lr;
#pragma unroll
        for (int i = 0; i < 4; ++i)
          qt[(size_t)(ob + i) * NPIX + p] = f2bf(acc[n][m][i]);
      }
  }
}

// ---------------------------------------------------------------------------
// Attention, lane = pixel. Wave = 64 consecutive pixels x 1 head x 1 dil.
// qkv_t channel-major: row o = which*128 + dil*64 + head*16 + c, col = pixel.
// ---------------------------------------------------------------------------
__global__ __launch_bounds__(256, 2)
void attn_kernel(const unsigned short* __restrict__ qt,
                 unsigned short* __restrict__ y) {
  const int t = threadIdx.x, lane = t & 63, head = t >> 6;
  const int dil = blockIdx.y, r = dil ? 2 : 1;
  const int p = blockIdx.x * 64 + lane;
  const int rem = p % (HW_ * HW_);
  const int yy = rem / HW_;
  const int xx = rem - yy * HW_;
  const int browq = dil * 64 + head * 16;

  // q[16]
  const unsigned short* qp = qt + (size_t)browq * NPIX + p;
  float q[16];
#pragma unroll
  for (int c = 0; c < 16; ++c) q[c] = bf2f(qp[(size_t)c * NPIX]);

  // neighbor offsets + validity
  int np[9];
  bool val[9];
#pragma unroll
  for (int jy = 0; jy < 3; ++jy)
#pragma unroll
    for (int jx = 0; jx < 3; ++jx) {
      const int j = jy * 3 + jx;
      const int dy = (jy - 1) * r, dx = (jx - 1) * r;
      val[j] = ((unsigned)(yy + dy) < HW_) && ((unsigned)(xx + dx) < HW_);
      int q_ = p + dy * HW_ + dx;
      np[j] = min(max(q_, 0), NPIX - 1);   // clamped; garbage masked later
    }

  // logits: l[j] = q . k_j  (9 independent FMA chains)
  float l[9];
#pragma unroll
  for (int j = 0; j < 9; ++j) l[j] = 0.f;
  const unsigned short* kp = qt + (size_t)(128 + browq) * NPIX;
#pragma unroll
  for (int c = 0; c < 16; ++c) {
    const float qc = q[c];
    const unsigned short* rp = kp + (size_t)c * NPIX;
#pragma unroll
    for (int j = 0; j < 9; ++j) l[j] += qc * bf2f(rp[np[j]]);
  }
#pragma unroll
  for (int j = 0; j < 9; ++j) l[j] = val[j] ? l[j] * 0.25f : 0.f;  // zero-pad

  // softmax over all 9 (invalid logits participate as 0, per reference)
  float mx = l[0];
#pragma unroll
  for (int j = 1; j < 9; ++j) mx = fmaxf(mx, l[j]);
  float e[9], s = 0.f;
#pragma unroll
  for (int j = 0; j < 9; ++j) { e[j] = __expf(l[j] - mx); s += e[j]; }
#pragma unroll
  for (int j = 0; j < 9; ++j) if (!val[j]) e[j] = 0.f;  // v_j = 0 for OOB
  const float inv = 1.0f / s;

  // o[c] = sum_j e_j * v_j[c]
  float o[16];
#pragma unroll
  for (int c = 0; c < 16; ++c) o[c] = 0.f;
  const unsigned short* vp = qt + (size_t)(256 + browq) * NPIX;
#pragma unroll
  for (int c = 0; c < 16; ++c) {
    const unsigned short* rp = vp + (size_t)c * NPIX;
#pragma unroll
    for (int j = 0; j < 9; ++j) o[c] += e[j] * bf2f(rp[np[j]]);
  }

  // write y[p][dil*64 + head*16 + c] bf16 (2 x short8; L2 write-combines)
  short8 h0, h1;
#pragma unroll
  for (int c = 0; c < 8; ++c) h0[c] = (short)f2bf(o[c] * inv);
#pragma unroll
  for (int c = 0; c < 8; ++c) h1[c] = (short)f2bf(o[c + 8] * inv);
  unsigned short* yp = y + (size_t)p * 128 + dil * 64 + head * 16;
  *(short8*)yp = h0;
  *(short8*)(yp + 8) = h1;
}

// ---------------------------------------------------------------------------
// GEMM2 (proj): C[p][o] = sum_k y[p][k] * proj_w[o][k] + b[o]; K=128.
// Tile 128x64, 256 threads, mfma 16x16x32 bf16 (round-2 kernel, A bf16).
// ---------------------------------------------------------------------------
__global__ __launch_bounds__(256, 3)
void proj_gemm(const unsigned short* __restrict__ Ag, const float* __restrict__ Wg,
               const float* __restrict__ bias, float* __restrict__ C, int N) {
  __shared__ short As[128 * 128];  // 32 KB
  __shared__ short Ws[64 * 128];   // 16 KB
  const int t = threadIdx.x;
  const int row0 = blockIdx.x * 128;
  const int col0 = blockIdx.y * 64;

  const short* A = (const short*)Ag + (size_t)row0 * 128;
#pragma unroll
  for (int it = 0; it < 8; ++it) {
    int f = t + it * 256;
    int row = f >> 4;
    short8 v = *(const short8*)(A + f * 8);
    int dst = (row * 256 + (f & 15) * 16) ^ ((row & 7) << 4);
    *(short8*)((char*)As + dst) = v;
  }
  {
    const float* W = Wg + (size_t)col0 * 128;
#pragma unroll
    for (int it = 0; it < 4; ++it) {
      int f = t + it * 256;
      int row = f >> 4;
      float4 x0 = *(const float4*)(W + f * 8);
      float4 x1 = *(const float4*)(W + f * 8 + 4);
      int dst = (row * 256 + (f & 15) * 16) ^ ((row & 7) << 4);
      *(short8*)((char*)Ws + dst) = cvt8(x0, x1);
    }
  }
  __syncthreads();

  const int lane = t & 63;
  const int w = t >> 6;
  const int wr = w & 1, wc = w >> 1;
  const int lr = lane & 15, lk = lane >> 4;

  f32x4 acc[4][2];
#pragma unroll
  for (int m = 0; m < 4; ++m)
#pragma unroll
    for (int n = 0; n < 2; ++n) acc[m][n] = 0.f;

#pragma unroll
  for (int kk = 0; kk < 4; ++kk) {
    short8 a[4], b[2];
#pragma unroll
    for (int m = 0; m < 4; ++m) {
      int row = wr * 64 + m * 16 + lr;
      int off = (row * 256 + kk * 64 + lk * 16) ^ ((row & 7) << 4);
      a[m] = *(const short8*)((const char*)As + off);
    }
#pragma unroll
    for (int n = 0; n < 2; ++n) {
      int row = wc * 32 + n * 16 + lr;
      int off = (row * 256 + kk * 64 + lk * 16) ^ ((row & 7) << 4);
      b[n] = *(const short8*)((const char*)Ws + off);
    }
#pragma unroll
    for (int m = 0; m < 4; ++m)
#pragma unroll
      for (int n = 0; n < 2; ++n)
        acc[m][n] = __builtin_amdgcn_mfma_f32_16x16x32_bf16(a[m], b[n], acc[m][n], 0, 0, 0);
  }

#pragma unroll
  for (int n = 0; n < 2; ++n) {
    int ccol = col0 + wc * 32 + n * 16 + lr;
    float bv = bias ? bias[ccol] : 0.f;
#pragma unroll
    for (int m = 0; m < 4; ++m) {
      int crow = row0 + wr * 64 + m * 16 + lk * 4;
#pragma unroll
      for (int i = 0; i < 4; ++i)
        C[(size_t)(crow + i) * N + ccol] = acc[m][n][i] + bv;
    }
  }
}

extern "C" void kernel_launch(void* const* d_in, const int* in_sizes, int n_in,
                              void* d_out, int out_size, void* d_ws, size_t ws_size,
                              hipStream_t stream) {
  const float* x      = (const float*)d_in[0];  // [2,160,160,128]
  const float* qkv_w  = (const float*)d_in[1];  // [384,128]
  const float* proj_w = (const float*)d_in[2];  // [128,128]
  const float* proj_b = (const float*)d_in[3];  // [128]
  float* out = (float*)d_out;                   // [2,160,160,128] fp32

  unsigned short* qkv_t = (unsigned short*)d_ws;            // [384][51200] bf16, 39.3 MB
  unsigned short* yws = qkv_t + (size_t)384 * NPIX;         // [51200][128] bf16, 13.1 MB

  // 1) QKV projection -> transposed bf16 qkv_t[o][p]
  qkv_gemm<<<NPIX / 64, 256, 0, stream>>>(x, qkv_w, qkv_t);

  // 2) Dilated neighborhood attention (lane = pixel) -> yws[p][c] bf16
  attn_kernel<<<dim3(NPIX / 64, 2), 256, 0, stream>>>(qkv_t, yws);

  // 3) Output projection + bias -> out fp32
  proj_gemm<<<dim3(NPIX / 128, 128 / 64), 256, 0, stream>>>(
      yws, proj_w, proj_b, out, 128);
}

// Round 4
// 139.702 us; speedup vs baseline: 38.4355x; 1.2041x over previous
//
#include <hip/hip_runtime.h>
#include <cstdint>

#define HW_ 160
#define NPIX (2*160*160)   // 51200 pixels (B*H*W)

typedef __attribute__((ext_vector_type(8))) short short8;
typedef __attribute__((ext_vector_type(4))) float f32x4;

// fp32 -> bf16 round-to-nearest-even
__device__ __forceinline__ unsigned short f2bf(float f) {
  union { float f; unsigned u; } v; v.f = f;
  unsigned r = v.u + 0x7fffu + ((v.u >> 16) & 1u);
  return (unsigned short)(r >> 16);
}
__device__ __forceinline__ float bflo(unsigned u) {  // low bf16 of packed pair
  union { unsigned u; float f; } v; v.u = u << 16; return v.f;
}
__device__ __forceinline__ float bfhi(unsigned u) {  // high bf16 of packed pair
  union { unsigned u; float f; } v; v.u = u & 0xffff0000u; return v.f;
}

__device__ __forceinline__ short8 cvt8(const float4& x0, const float4& x1) {
  short8 h;
  h[0] = (short)f2bf(x0.x); h[1] = (short)f2bf(x0.y);
  h[2] = (short)f2bf(x0.z); h[3] = (short)f2bf(x0.w);
  h[4] = (short)f2bf(x1.x); h[5] = (short)f2bf(x1.y);
  h[6] = (short)f2bf(x1.z); h[7] = (short)f2bf(x1.w);
  return h;
}

// ---------------------------------------------------------------------------
// One-time fp32 -> bf16 weight conversion: qkv_w (49152) ++ proj_w (16384).
// ---------------------------------------------------------------------------
__global__ __launch_bounds__(256)
void cvt_w(const float* __restrict__ qw, const float* __restrict__ pw,
           unsigned short* __restrict__ dst) {
  int i = (blockIdx.x * 256 + threadIdx.x) * 4;
  const float* src = (i < 49152) ? (qw + i) : (pw + (i - 49152));
  float4 v = *(const float4*)src;
  dst[i] = f2bf(v.x); dst[i + 1] = f2bf(v.y);
  dst[i + 2] = f2bf(v.z); dst[i + 3] = f2bf(v.w);
}

// ---------------------------------------------------------------------------
// GEMM1: qt2[o/2][p] = packed bf16 pair of sum_k x[p][k]*qkv_w[o][k].
// Block = 64 pixels x 192 outputs (3 o-tiles); grid (800, 2).
// Operand-swapped MFMA -> D row = o, col = pixel.
// ---------------------------------------------------------------------------
__global__ __launch_bounds__(256, 4)
void qkv_gemm(const float* __restrict__ x, const unsigned short* __restrict__ wq,
              unsigned int* __restrict__ qt2) {
  __shared__ short As[64 * 128];  // 16 KB, xor-swizzled
  const int t = threadIdx.x;
  const int p0 = blockIdx.x * 64;
  const int og = blockIdx.y;      // o-group: 0 -> [0,192), 1 -> [192,384)

  const float* A = x + (size_t)p0 * 128;
#pragma unroll
  for (int i = 0; i < 4; ++i) {
    int f = t + i * 256;           // 16B-chunk id (1024 total)
    int row = f >> 4;
    float4 x0 = *(const float4*)(A + f * 8);
    float4 x1 = *(const float4*)(A + f * 8 + 4);
    int dst = (row * 256 + (f & 15) * 16) ^ ((row & 7) << 4);
    *(short8*)((char*)As + dst) = cvt8(x0, x1);
  }
  __syncthreads();

  const int lane = t & 63, wv = t >> 6;
  const int wp = wv & 1, wc = wv >> 1;   // pixel-half / o-half
  const int lr = lane & 15, lk = lane >> 4;

  // hoist pixel-fragments (constant across o-loop)
  short8 af[2][4];
#pragma unroll
  for (int m = 0; m < 2; ++m)
#pragma unroll
    for (int kk = 0; kk < 4; ++kk) {
      int row = wp * 32 + m * 16 + lr;
      int off = (row * 256 + kk * 64 + lk * 16) ^ ((row & 7) << 4);
      af[m][kk] = *(const short8*)((const char*)As + off);
    }

#pragma unroll
  for (int it = 0; it < 3; ++it) {
    const int o0 = og * 192 + it * 64 + wc * 32;
    short8 bfr[2][4];
#pragma unroll
    for (int n = 0; n < 2; ++n) {
      const unsigned short* wr_ = wq + (size_t)(o0 + n * 16 + lr) * 128;
#pragma unroll
      for (int kk = 0; kk < 4; ++kk)
        bfr[n][kk] = *(const short8*)(wr_ + kk * 32 + lk * 8);
    }
    f32x4 acc[2][2];
#pragma unroll
    for (int n = 0; n < 2; ++n)
#pragma unroll
      for (int m = 0; m < 2; ++m) acc[n][m] = 0.f;
#pragma unroll
    for (int kk = 0; kk < 4; ++kk)
#pragma unroll
      for (int n = 0; n < 2; ++n)
#pragma unroll
        for (int m = 0; m < 2; ++m)
          acc[n][m] = __builtin_amdgcn_mfma_f32_16x16x32_bf16(
              bfr[n][kk], af[m][kk], acc[n][m], 0, 0, 0);
    // epilogue: D row = o (lk*4+i), col = pixel (lr); pack 2 o-rows per uint.
#pragma unroll
    for (int n = 0; n < 2; ++n)
#pragma unroll
      for (int m = 0; m < 2; ++m) {
        int ob = o0 + n * 16 + lk * 4;       // ob % 4 == 0
        int p = p0 + wp * 32 + m * 16 + lr;
        unsigned u0 = ((unsigned)f2bf(acc[n][m][1]) << 16) | f2bf(acc[n][m][0]);
        unsigned u1 = ((unsigned)f2bf(acc[n][m][3]) << 16) | f2bf(acc[n][m][2]);
        qt2[(size_t)(ob >> 1) * NPIX + p] = u0;
        qt2[(size_t)((ob >> 1) + 1) * NPIX + p] = u1;
      }
  }
}

// ---------------------------------------------------------------------------
// Attention, lane = pixel, channel-pairs packed in uint rows.
// qt2 rows: o/2 for o = which*128 + dil*64 + head*16 + c. Wave = 64 pixels.
// ---------------------------------------------------------------------------
__global__ __launch_bounds__(256, 2)
void attn_kernel(const unsigned int* __restrict__ qt2,
                 unsigned short* __restrict__ y) {
  const int t = threadIdx.x, lane = t & 63, head = t >> 6;
  const int dil = blockIdx.y, r = dil ? 2 : 1;
  const int p = blockIdx.x * 64 + lane;
  const int rem = p % (HW_ * HW_);
  const int yy = rem / HW_;
  const int xx = rem - yy * HW_;
  const int brow2 = (dil * 64 + head * 16) >> 1;   // uint-row base (q)

  // q[16] via 8 packed loads
  const unsigned int* qp = qt2 + (size_t)brow2 * NPIX + p;
  float q[16];
#pragma unroll
  for (int c2 = 0; c2 < 8; ++c2) {
    unsigned u = qp[(size_t)c2 * NPIX];
    q[2 * c2] = bflo(u); q[2 * c2 + 1] = bfhi(u);
  }

  // neighbor offsets + validity
  int np[9];
  bool val[9];
#pragma unroll
  for (int jy = 0; jy < 3; ++jy)
#pragma unroll
    for (int jx = 0; jx < 3; ++jx) {
      const int j = jy * 3 + jx;
      const int dy = (jy - 1) * r, dx = (jx - 1) * r;
      val[j] = ((unsigned)(yy + dy) < HW_) && ((unsigned)(xx + dx) < HW_);
      int q_ = p + dy * HW_ + dx;
      np[j] = min(max(q_, 0), NPIX - 1);   // clamped; garbage masked later
    }

  // logits
  float l[9];
#pragma unroll
  for (int j = 0; j < 9; ++j) l[j] = 0.f;
  const unsigned int* kp = qt2 + (size_t)(64 + brow2) * NPIX;
#pragma unroll
  for (int c2 = 0; c2 < 8; ++c2) {
    const unsigned int* rp = kp + (size_t)c2 * NPIX;
    const float qa = q[2 * c2], qb = q[2 * c2 + 1];
#pragma unroll
    for (int j = 0; j < 9; ++j) {
      unsigned u = rp[np[j]];
      l[j] += qa * bflo(u) + qb * bfhi(u);
    }
  }
#pragma unroll
  for (int j = 0; j < 9; ++j) l[j] = val[j] ? l[j] * 0.25f : 0.f;  // zero-pad

  // softmax over all 9 (invalid logits participate as 0, per reference)
  float mx = l[0];
#pragma unroll
  for (int j = 1; j < 9; ++j) mx = fmaxf(mx, l[j]);
  float e[9], s = 0.f;
#pragma unroll
  for (int j = 0; j < 9; ++j) { e[j] = __expf(l[j] - mx); s += e[j]; }
#pragma unroll
  for (int j = 0; j < 9; ++j) if (!val[j]) e[j] = 0.f;  // v_j = 0 for OOB
  const float inv = 1.0f / s;

  // o[c] = sum_j e_j * v_j[c]
  float o[16];
#pragma unroll
  for (int c = 0; c < 16; ++c) o[c] = 0.f;
  const unsigned int* vp = qt2 + (size_t)(128 + brow2) * NPIX;
#pragma unroll
  for (int c2 = 0; c2 < 8; ++c2) {
    const unsigned int* rp = vp + (size_t)c2 * NPIX;
#pragma unroll
    for (int j = 0; j < 9; ++j) {
      unsigned u = rp[np[j]];
      o[2 * c2] += e[j] * bflo(u);
      o[2 * c2 + 1] += e[j] * bfhi(u);
    }
  }

  short8 h0, h1;
#pragma unroll
  for (int c = 0; c < 8; ++c) h0[c] = (short)f2bf(o[c] * inv);
#pragma unroll
  for (int c = 0; c < 8; ++c) h1[c] = (short)f2bf(o[c + 8] * inv);
  unsigned short* yp = y + (size_t)p * 128 + dil * 64 + head * 16;
  *(short8*)yp = h0;
  *(short8*)(yp + 8) = h1;
}

// ---------------------------------------------------------------------------
// GEMM2 (proj): C[p][o] = sum_k y[p][k]*proj_w[o][k] + b[o]; K=128.
// Block = 64 pixels x ALL 128 outputs; whole W (bf16) in LDS. 512 threads.
// ---------------------------------------------------------------------------
__global__ __launch_bounds__(512, 4)
void proj_gemm(const unsigned short* __restrict__ Yg,
               const unsigned short* __restrict__ wpb,
               const float* __restrict__ bias, float* __restrict__ C) {
  __shared__ short Ys[64 * 128];   // 16 KB
  __shared__ short Ws[128 * 128];  // 32 KB
  const int t = threadIdx.x;
  const int p0 = blockIdx.x * 64;

  const short* A = (const short*)Yg + (size_t)p0 * 128;
#pragma unroll
  for (int i = 0; i < 2; ++i) {
    int f = t + i * 512;
    int row = f >> 4;
    int dst = (row * 256 + (f & 15) * 16) ^ ((row & 7) << 4);
    *(short8*)((char*)Ys + dst) = *(const short8*)(A + f * 8);
  }
#pragma unroll
  for (int i = 0; i < 4; ++i) {
    int f = t + i * 512;
    int row = f >> 4;
    int dst = (row * 256 + (f & 15) * 16) ^ ((row & 7) << 4);
    *(short8*)((char*)Ws + dst) = *(const short8*)((const short*)wpb + f * 8);
  }
  __syncthreads();

  const int lane = t & 63, wv = t >> 6;
  const int wq_ = wv & 3, wo = wv >> 2;   // pixel-quarter / o-half
  const int lr = lane & 15, lk = lane >> 4;

  short8 a[4], b[4][4];
#pragma unroll
  for (int kk = 0; kk < 4; ++kk) {
    int row = wq_ * 16 + lr;
    int off = (row * 256 + kk * 64 + lk * 16) ^ ((row & 7) << 4);
    a[kk] = *(const short8*)((const char*)Ys + off);
  }
#pragma unroll
  for (int n = 0; n < 4; ++n)
#pragma unroll
    for (int kk = 0; kk < 4; ++kk) {
      int row = wo * 64 + n * 16 + lr;
      int off = (row * 256 + kk * 64 + lk * 16) ^ ((row & 7) << 4);
      b[n][kk] = *(const short8*)((const char*)Ws + off);
    }

  f32x4 acc[4];
#pragma unroll
  for (int n = 0; n < 4; ++n) acc[n] = 0.f;
#pragma unroll
  for (int kk = 0; kk < 4; ++kk)
#pragma unroll
    for (int n = 0; n < 4; ++n)
      acc[n] = __builtin_amdgcn_mfma_f32_16x16x32_bf16(a[kk], b[n][kk], acc[n], 0, 0, 0);

#pragma unroll
  for (int n = 0; n < 4; ++n) {
    int ccol = wo * 64 + n * 16 + lr;
    float bv = bias[ccol];
    int crow = p0 + wq_ * 16 + lk * 4;
#pragma unroll
    for (int i = 0; i < 4; ++i)
      C[(size_t)(crow + i) * 128 + ccol] = acc[n][i] + bv;
  }
}

extern "C" void kernel_launch(void* const* d_in, const int* in_sizes, int n_in,
                              void* d_out, int out_size, void* d_ws, size_t ws_size,
                              hipStream_t stream) {
  const float* x      = (const float*)d_in[0];  // [2,160,160,128]
  const float* qkv_w  = (const float*)d_in[1];  // [384,128]
  const float* proj_w = (const float*)d_in[2];  // [128,128]
  const float* proj_b = (const float*)d_in[3];  // [128]
  float* out = (float*)d_out;                   // [2,160,160,128] fp32

  unsigned int* qt2 = (unsigned int*)d_ws;                        // [192][51200] uint, 39.3 MB
  unsigned short* yws = (unsigned short*)(qt2 + (size_t)192 * NPIX); // [51200][128] bf16, 13.1 MB
  unsigned short* wbf = yws + (size_t)NPIX * 128;                 // 65536 bf16, 128 KB
  const unsigned short* wqbf = wbf;            // [384][128]
  const unsigned short* wpbf = wbf + 49152;    // [128][128]

  // 0) one-time weight conversion (re-run每 launch; ws is re-poisoned)
  cvt_w<<<64, 256, 0, stream>>>(qkv_w, proj_w, wbf);

  // 1) QKV projection -> packed transposed bf16 qt2[o/2][p]
  qkv_gemm<<<dim3(NPIX / 64, 2), 256, 0, stream>>>(x, wqbf, qt2);

  // 2) Dilated neighborhood attention -> yws[p][c] bf16
  attn_kernel<<<dim3(NPIX / 64, 2), 256, 0, stream>>>(qt2, yws);

  // 3) Output projection + bias -> out fp32
  proj_gemm<<<NPIX / 64, 512, 0, stream>>>(yws, wpbf, proj_b, out);
}

// Round 5
// 137.563 us; speedup vs baseline: 39.0333x; 1.0156x over previous
//
#include <hip/hip_runtime.h>
#include <cstdint>

#define HW_ 160
#define NPIX (2*160*160)   // 51200 pixels (B*H*W)

typedef __attribute__((ext_vector_type(8))) short short8;
typedef __attribute__((ext_vector_type(4))) float f32x4;

// fp32 -> bf16 round-to-nearest-even
__device__ __forceinline__ unsigned short f2bf(float f) {
  union { float f; unsigned u; } v; v.f = f;
  unsigned r = v.u + 0x7fffu + ((v.u >> 16) & 1u);
  return (unsigned short)(r >> 16);
}
__device__ __forceinline__ float bflo(unsigned u) {  // low bf16 of packed pair
  union { unsigned u; float f; } v; v.u = u << 16; return v.f;
}
__device__ __forceinline__ float bfhi(unsigned u) {  // high bf16 of packed pair
  union { unsigned u; float f; } v; v.u = u & 0xffff0000u; return v.f;
}

__device__ __forceinline__ short8 cvt8(const float4& x0, const float4& x1) {
  short8 h;
  h[0] = (short)f2bf(x0.x); h[1] = (short)f2bf(x0.y);
  h[2] = (short)f2bf(x0.z); h[3] = (short)f2bf(x0.w);
  h[4] = (short)f2bf(x1.x); h[5] = (short)f2bf(x1.y);
  h[6] = (short)f2bf(x1.z); h[7] = (short)f2bf(x1.w);
  return h;
}

// ---------------------------------------------------------------------------
// One-time fp32 -> bf16 conversion of qkv_w (49152 elems).
// ---------------------------------------------------------------------------
__global__ __launch_bounds__(256)
void cvt_w(const float* __restrict__ qw, unsigned short* __restrict__ dst) {
  int i = (blockIdx.x * 256 + threadIdx.x) * 4;
  float4 v = *(const float4*)(qw + i);
  dst[i] = f2bf(v.x); dst[i + 1] = f2bf(v.y);
  dst[i + 2] = f2bf(v.z); dst[i + 3] = f2bf(v.w);
}

// ---------------------------------------------------------------------------
// GEMM1: qt2[o/2][p] = packed bf16 pair of sum_k x[p][k]*qkv_w[o][k].
// Block = 64 pixels x 192 outputs (3 o-tiles); grid (800, 2).
// Operand-swapped MFMA -> D row = o, col = pixel.
// ---------------------------------------------------------------------------
__global__ __launch_bounds__(256, 4)
void qkv_gemm(const float* __restrict__ x, const unsigned short* __restrict__ wq,
              unsigned int* __restrict__ qt2) {
  __shared__ short As[64 * 128];  // 16 KB, xor-swizzled
  const int t = threadIdx.x;
  const int p0 = blockIdx.x * 64;
  const int og = blockIdx.y;      // o-group: 0 -> [0,192), 1 -> [192,384)

  const float* A = x + (size_t)p0 * 128;
#pragma unroll
  for (int i = 0; i < 4; ++i) {
    int f = t + i * 256;           // 16B-chunk id (1024 total)
    int row = f >> 4;
    float4 x0 = *(const float4*)(A + f * 8);
    float4 x1 = *(const float4*)(A + f * 8 + 4);
    int dst = (row * 256 + (f & 15) * 16) ^ ((row & 7) << 4);
    *(short8*)((char*)As + dst) = cvt8(x0, x1);
  }
  __syncthreads();

  const int lane = t & 63, wv = t >> 6;
  const int wp = wv & 1, wc = wv >> 1;   // pixel-half / o-half
  const int lr = lane & 15, lk = lane >> 4;

  // hoist pixel-fragments (constant across o-loop)
  short8 af[2][4];
#pragma unroll
  for (int m = 0; m < 2; ++m)
#pragma unroll
    for (int kk = 0; kk < 4; ++kk) {
      int row = wp * 32 + m * 16 + lr;
      int off = (row * 256 + kk * 64 + lk * 16) ^ ((row & 7) << 4);
      af[m][kk] = *(const short8*)((const char*)As + off);
    }

#pragma unroll
  for (int it = 0; it < 3; ++it) {
    const int o0 = og * 192 + it * 64 + wc * 32;
    short8 bfr[2][4];
#pragma unroll
    for (int n = 0; n < 2; ++n) {
      const unsigned short* wr_ = wq + (size_t)(o0 + n * 16 + lr) * 128;
#pragma unroll
      for (int kk = 0; kk < 4; ++kk)
        bfr[n][kk] = *(const short8*)(wr_ + kk * 32 + lk * 8);
    }
    f32x4 acc[2][2];
#pragma unroll
    for (int n = 0; n < 2; ++n)
#pragma unroll
      for (int m = 0; m < 2; ++m) acc[n][m] = 0.f;
#pragma unroll
    for (int kk = 0; kk < 4; ++kk)
#pragma unroll
      for (int n = 0; n < 2; ++n)
#pragma unroll
        for (int m = 0; m < 2; ++m)
          acc[n][m] = __builtin_amdgcn_mfma_f32_16x16x32_bf16(
              bfr[n][kk], af[m][kk], acc[n][m], 0, 0, 0);
    // epilogue: D row = o (lk*4+i), col = pixel (lr); pack 2 o-rows per uint.
#pragma unroll
    for (int n = 0; n < 2; ++n)
#pragma unroll
      for (int m = 0; m < 2; ++m) {
        int ob = o0 + n * 16 + lk * 4;       // ob % 4 == 0
        int p = p0 + wp * 32 + m * 16 + lr;
        unsigned u0 = ((unsigned)f2bf(acc[n][m][1]) << 16) | f2bf(acc[n][m][0]);
        unsigned u1 = ((unsigned)f2bf(acc[n][m][3]) << 16) | f2bf(acc[n][m][2]);
        qt2[(size_t)(ob >> 1) * NPIX + p] = u0;
        qt2[(size_t)((ob >> 1) + 1) * NPIX + p] = u1;
      }
  }
}

// ---------------------------------------------------------------------------
// Fused attention + output projection.
// Block = 64 pixels, 512 threads (8 waves). Wave wv: dil = wv>>2, head = wv&3,
// lane = pixel. Attention result written to LDS Ys[64][128] (bf16, swizzled),
// then proj MFMA out of LDS: C[p][o] = sum_k y[p][k]*proj_w[o][k] + b[o].
// ---------------------------------------------------------------------------
__global__ __launch_bounds__(512, 4)
void attn_proj(const unsigned int* __restrict__ qt2,
               const float* __restrict__ wp_f32,
               const float* __restrict__ bias, float* __restrict__ C) {
  __shared__ short Ys[64 * 128];   // 16 KB
  __shared__ short Ws[128 * 128];  // 32 KB
  const int t = threadIdx.x;
  const int p0 = blockIdx.x * 64;

  // ---- stage proj weights fp32 -> bf16 into LDS (swizzled) ----
#pragma unroll
  for (int i = 0; i < 4; ++i) {
    int f = t + i * 512;           // 16B-chunk id (2048 total)
    int row = f >> 4;
    float4 x0 = *(const float4*)(wp_f32 + f * 8);
    float4 x1 = *(const float4*)(wp_f32 + f * 8 + 4);
    int dst = (row * 256 + (f & 15) * 16) ^ ((row & 7) << 4);
    *(short8*)((char*)Ws + dst) = cvt8(x0, x1);
  }

  // ---- attention: wave = (dil, head), lane = pixel ----
  const int lane = t & 63, wv = t >> 6;
  const int dil = wv >> 2, head = wv & 3;
  const int r = dil ? 2 : 1;
  const int p = p0 + lane;
  const int rem = p % (HW_ * HW_);
  const int yy = rem / HW_;
  const int xx = rem - yy * HW_;
  const int brow2 = (dil * 64 + head * 16) >> 1;   // uint-row base (q)

  // q[16] via 8 packed loads
  const unsigned int* qp = qt2 + (size_t)brow2 * NPIX + p;
  float q[16];
#pragma unroll
  for (int c2 = 0; c2 < 8; ++c2) {
    unsigned u = qp[(size_t)c2 * NPIX];
    q[2 * c2] = bflo(u); q[2 * c2 + 1] = bfhi(u);
  }

  // neighbor offsets + validity
  int np[9];
  bool val[9];
#pragma unroll
  for (int jy = 0; jy < 3; ++jy)
#pragma unroll
    for (int jx = 0; jx < 3; ++jx) {
      const int j = jy * 3 + jx;
      const int dy = (jy - 1) * r, dx = (jx - 1) * r;
      val[j] = ((unsigned)(yy + dy) < HW_) && ((unsigned)(xx + dx) < HW_);
      int q_ = p + dy * HW_ + dx;
      np[j] = min(max(q_, 0), NPIX - 1);   // clamped; garbage masked later
    }

  // logits
  float l[9];
#pragma unroll
  for (int j = 0; j < 9; ++j) l[j] = 0.f;
  const unsigned int* kp = qt2 + (size_t)(64 + brow2) * NPIX;
#pragma unroll
  for (int c2 = 0; c2 < 8; ++c2) {
    const unsigned int* rp = kp + (size_t)c2 * NPIX;
    const float qa = q[2 * c2], qb = q[2 * c2 + 1];
#pragma unroll
    for (int j = 0; j < 9; ++j) {
      unsigned u = rp[np[j]];
      l[j] += qa * bflo(u) + qb * bfhi(u);
    }
  }
#pragma unroll
  for (int j = 0; j < 9; ++j) l[j] = val[j] ? l[j] * 0.25f : 0.f;  // zero-pad

  // softmax over all 9 (invalid logits participate as 0, per reference)
  float mx = l[0];
#pragma unroll
  for (int j = 1; j < 9; ++j) mx = fmaxf(mx, l[j]);
  float e[9], s = 0.f;
#pragma unroll
  for (int j = 0; j < 9; ++j) { e[j] = __expf(l[j] - mx); s += e[j]; }
#pragma unroll
  for (int j = 0; j < 9; ++j) if (!val[j]) e[j] = 0.f;  // v_j = 0 for OOB
  const float inv = 1.0f / s;

  // o[c] = sum_j e_j * v_j[c]
  float o[16];
#pragma unroll
  for (int c = 0; c < 16; ++c) o[c] = 0.f;
  const unsigned int* vp = qt2 + (size_t)(128 + brow2) * NPIX;
#pragma unroll
  for (int c2 = 0; c2 < 8; ++c2) {
    const unsigned int* rp = vp + (size_t)c2 * NPIX;
#pragma unroll
    for (int j = 0; j < 9; ++j) {
      unsigned u = rp[np[j]];
      o[2 * c2] += e[j] * bflo(u);
      o[2 * c2 + 1] += e[j] * bfhi(u);
    }
  }

  // write y-slice to LDS: row = lane, cols [dil*64+head*16, +16), swizzled
  {
    short8 h0, h1;
#pragma unroll
    for (int c = 0; c < 8; ++c) h0[c] = (short)f2bf(o[c] * inv);
#pragma unroll
    for (int c = 0; c < 8; ++c) h1[c] = (short)f2bf(o[c + 8] * inv);
    int colb = (dil * 64 + head * 16) * 2;
    int base = (lane * 256 + colb) ^ ((lane & 7) << 4);
    *(short8*)((char*)Ys + base) = h0;
    int base2 = (lane * 256 + colb + 16) ^ ((lane & 7) << 4);
    *(short8*)((char*)Ys + base2) = h1;
  }
  __syncthreads();

  // ---- proj: wave -> (pixel-quarter wq_, o-half wo) ----
  const int wq_ = wv & 3, wo = wv >> 2;
  const int lr = lane & 15, lk = lane >> 4;

  short8 a[4];
#pragma unroll
  for (int kk = 0; kk < 4; ++kk) {
    int row = wq_ * 16 + lr;
    int off = (row * 256 + kk * 64 + lk * 16) ^ ((row & 7) << 4);
    a[kk] = *(const short8*)((const char*)Ys + off);
  }

  f32x4 acc[4];
#pragma unroll
  for (int n = 0; n < 4; ++n) acc[n] = 0.f;
#pragma unroll
  for (int kk = 0; kk < 4; ++kk) {
    short8 b[4];
#pragma unroll
    for (int n = 0; n < 4; ++n) {
      int row = wo * 64 + n * 16 + lr;
      int off = (row * 256 + kk * 64 + lk * 16) ^ ((row & 7) << 4);
      b[n] = *(const short8*)((const char*)Ws + off);
    }
#pragma unroll
    for (int n = 0; n < 4; ++n)
      acc[n] = __builtin_amdgcn_mfma_f32_16x16x32_bf16(a[kk], b[n], acc[n], 0, 0, 0);
  }

#pragma unroll
  for (int n = 0; n < 4; ++n) {
    int ccol = wo * 64 + n * 16 + lr;
    float bv = bias[ccol];
    int crow = p0 + wq_ * 16 + lk * 4;
#pragma unroll
    for (int i = 0; i < 4; ++i)
      C[(size_t)(crow + i) * 128 + ccol] = acc[n][i] + bv;
  }
}

extern "C" void kernel_launch(void* const* d_in, const int* in_sizes, int n_in,
                              void* d_out, int out_size, void* d_ws, size_t ws_size,
                              hipStream_t stream) {
  const float* x      = (const float*)d_in[0];  // [2,160,160,128]
  const float* qkv_w  = (const float*)d_in[1];  // [384,128]
  const float* proj_w = (const float*)d_in[2];  // [128,128]
  const float* proj_b = (const float*)d_in[3];  // [128]
  float* out = (float*)d_out;                   // [2,160,160,128] fp32

  unsigned int* qt2 = (unsigned int*)d_ws;                   // [192][51200] uint, 39.3 MB
  unsigned short* wqbf = (unsigned short*)(qt2 + (size_t)192 * NPIX);  // [384][128] bf16

  // 0) qkv weight conversion fp32 -> bf16
  cvt_w<<<48, 256, 0, stream>>>(qkv_w, wqbf);

  // 1) QKV projection -> packed transposed bf16 qt2[o/2][p]
  qkv_gemm<<<dim3(NPIX / 64, 2), 256, 0, stream>>>(x, wqbf, qt2);

  // 2+3) Fused dilated neighborhood attention + output projection
  attn_proj<<<NPIX / 64, 512, 0, stream>>>(qt2, proj_w, proj_b, out);
}